// Round 1
// baseline (206.335 us; speedup 1.0000x reference)
//
#include <hip/hip_runtime.h>
#include <math.h>

// Problem constants (from reference): N=100000, D=64, B=4096, W=10, L=8, M=128, T=64
constexpr int D_ = 64;
constexpr int B_ = 4096;
constexpr int W_ = 10;
constexpr int L_ = 8;
constexpr int M_ = 128;
constexpr int T_ = 64;
constexpr int NWALK = B_ * W_;   // 40960 independent walkers

// One thread per walker. All reductions/cumsums are kept strictly sequential in
// f32, with true IEEE division (/0.1f and e/sum) and precise cosf/expf, so the
// inverse-CDF comparisons (cdf < r) and restart comparisons (r < p) reproduce
// the reference's float32 decisions: the sampled node id is categorical, and a
// single comparison flip would blow absmax past the 2% threshold.
__global__ __launch_bounds__(256) void walk_kernel(
    const int*   __restrict__ nbr_ids,      // [N,D]
    const float* __restrict__ nbr_time,     // [N,D]
    const int*   __restrict__ nbr_cnt,      // [N]
    const int*   __restrict__ start_nodes,  // [B]
    const float* __restrict__ start_times,  // [B]
    const float* __restrict__ mem,          // [N,M]
    const float* __restrict__ time_w,       // [T]
    const float* __restrict__ time_b,       // [T]
    const float* __restrict__ restart_w,    // [M+T]
    const float* __restrict__ restart_b,    // [1]
    const float* __restrict__ rand_restart, // [L,B,W]
    const float* __restrict__ rand_neighbor,// [L,B,W]
    float* __restrict__ out_nodes,          // [B,W,L+1] (as f32)
    float* __restrict__ out_times,          // [B,W,L+1]
    float* __restrict__ out_probs)          // [B,W,L]
{
    const int gid = blockIdx.x * blockDim.x + threadIdx.x;
    if (gid >= NWALK) return;
    const int b = gid / W_;

    const int   sn = start_nodes[b];
    const float st = start_times[b];
    int   cur_n = sn;
    float cur_t = st;

    float* __restrict__ on = out_nodes + (size_t)gid * (L_ + 1);
    float* __restrict__ ot = out_times + (size_t)gid * (L_ + 1);
    float* __restrict__ op = out_probs + (size_t)gid * L_;
    on[0] = (float)sn;
    ot[0] = st;

    const float rb = restart_b[0];

    for (int l = 0; l < L_; ++l) {
        // ---- restart probability: sigmoid(mem . w[:M] + tenc . w[M:] + b) ----
        const float* __restrict__ mrow = mem + (size_t)cur_n * M_;
        float accm = 0.f;
        #pragma unroll 8
        for (int m = 0; m < M_; ++m) accm += mrow[m] * restart_w[m];
        float acct = 0.f;
        #pragma unroll 8
        for (int t = 0; t < T_; ++t)
            acct += cosf(cur_t * time_w[t] + time_b[t]) * restart_w[M_ + t];
        const float logits = accm + acct + rb;
        const float p = 1.f / (1.f + expf(-logits));
        const bool restart = rand_restart[(size_t)l * NWALK + gid] < p;

        // ---- temporal neighbor softmax + inverse-CDF sample ----
        const int*   __restrict__ ids = nbr_ids  + (size_t)cur_n * D_;
        const float* __restrict__ nts = nbr_time + (size_t)cur_n * D_;
        const int cnt = nbr_cnt[cur_n];

        float sc[D_];
        float mx = -1e9f;
        bool  hv = false;
        #pragma unroll
        for (int j = 0; j < D_; ++j) {
            const float tj = nts[j];
            const bool  v  = (tj < cur_t) && (j < cnt);
            const float s  = v ? (tj - cur_t) / 0.1f : -1e9f;  // true division by 0.1f
            sc[j] = s;
            mx = fmaxf(mx, s);
            hv = hv || v;
        }
        float ssum = 0.f;
        #pragma unroll
        for (int j = 0; j < D_; ++j) {
            const float e = expf(sc[j] - mx);
            sc[j] = e;
            ssum += e;                                   // sequential sum
        }
        const float r = rand_neighbor[(size_t)l * NWALK + gid];
        float cdf = 0.f;
        int   idx = 0;
        #pragma unroll
        for (int j = 0; j < D_; ++j) {
            cdf += sc[j] / ssum;                         // probs then sequential cumsum
            idx += (cdf < r) ? 1 : 0;
        }
        if (idx > D_ - 1) idx = D_ - 1;

        const int   sel_id = ids[idx];
        const float sel_t  = nts[idx];
        const int   step_n = hv ? sel_id : cur_n;
        const float step_t = hv ? sel_t  : cur_t;
        cur_n = restart ? sn : step_n;
        cur_t = restart ? st : step_t;

        on[l + 1] = (float)cur_n;
        ot[l + 1] = cur_t;
        op[l]     = p;
    }
}

extern "C" void kernel_launch(void* const* d_in, const int* in_sizes, int n_in,
                              void* d_out, int out_size, void* d_ws, size_t ws_size,
                              hipStream_t stream) {
    const int*   nbr_ids       = (const int*)  d_in[0];
    const float* nbr_time      = (const float*)d_in[1];
    const int*   nbr_cnt       = (const int*)  d_in[2];
    const int*   start_nodes   = (const int*)  d_in[3];
    const float* start_times   = (const float*)d_in[4];
    const float* memst         = (const float*)d_in[5];
    const float* time_w        = (const float*)d_in[6];
    const float* time_b        = (const float*)d_in[7];
    const float* restart_w     = (const float*)d_in[8];
    const float* restart_b     = (const float*)d_in[9];
    const float* rand_restart  = (const float*)d_in[10];
    const float* rand_neighbor = (const float*)d_in[11];

    float* out_nodes = (float*)d_out;
    float* out_times = out_nodes + (size_t)B_ * W_ * (L_ + 1);
    float* out_probs = out_times + (size_t)B_ * W_ * (L_ + 1);

    const int threads = 256;
    const int blocks  = (NWALK + threads - 1) / threads;
    hipLaunchKernelGGL(walk_kernel, dim3(blocks), dim3(threads), 0, stream,
                       nbr_ids, nbr_time, nbr_cnt, start_nodes, start_times,
                       memst, time_w, time_b, restart_w, restart_b,
                       rand_restart, rand_neighbor,
                       out_nodes, out_times, out_probs);
}

// Round 2
// 81.980 us; speedup vs baseline: 2.5169x; 2.5169x over previous
//
#include <hip/hip_runtime.h>
#include <math.h>

// N=100000, D=64, B=4096, W=10, L=8, M=128, T=64
constexpr int D_ = 64;
constexpr int B_ = 4096;
constexpr int W_ = 10;
constexpr int L_ = 8;
constexpr int M_ = 128;
constexpr int T_ = 64;
constexpr int NWALK = B_ * W_;   // 40960 walkers
constexpr int K_ = 8;            // lanes per walker

// 8 lanes cooperate on one walker. All order-sensitive f32 reductions (the two
// restart-logit dots, the softmax sum, the CDF cumsum) are computed as an
// 8-chunk sequential RELAY across lanes (shfl_up handoff), reproducing the
// exact left-to-right fold of the previous (passing) one-thread version —
// including fmac contraction for the dots and true IEEE division for /0.1f and
// e/ssum. Max (fmaxf) and integer counts are associative, so those use shuffle
// trees. Elementwise cosf/expf/div are computed lane-parallel (identical
// per-element expressions => identical bits). Decisions are therefore
// bit-identical to the verified kernel; this change only raises occupancy
// (0.625 -> ~4-5 waves/SIMD) to hide the divergent gather latency.
__global__ __launch_bounds__(256) void walk_kernel(
    const int*   __restrict__ nbr_ids,      // [N,D]
    const float* __restrict__ nbr_time,     // [N,D]
    const int*   __restrict__ nbr_cnt,      // [N]
    const int*   __restrict__ start_nodes,  // [B]
    const float* __restrict__ start_times,  // [B]
    const float* __restrict__ mem,          // [N,M]
    const float* __restrict__ time_w,       // [T]
    const float* __restrict__ time_b,       // [T]
    const float* __restrict__ restart_w,    // [M+T]
    const float* __restrict__ restart_b,    // [1]
    const float* __restrict__ rand_restart, // [L,B,W]
    const float* __restrict__ rand_neighbor,// [L,B,W]
    float* __restrict__ out_nodes,          // [B,W,L+1] (as f32)
    float* __restrict__ out_times,          // [B,W,L+1]
    float* __restrict__ out_probs)          // [B,W,L]
{
    const int tid = blockIdx.x * blockDim.x + threadIdx.x;
    const int gid = tid >> 3;          // walker id
    const int r   = tid & 7;           // lane-in-group
    if (gid >= NWALK) return;
    const int b = gid / W_;

    const int   sn = start_nodes[b];
    const float st = start_times[b];
    int   cur_n = sn;
    float cur_t = st;

    float* __restrict__ on = out_nodes + (size_t)gid * (L_ + 1);
    float* __restrict__ ot = out_times + (size_t)gid * (L_ + 1);
    float* __restrict__ op = out_probs + (size_t)gid * L_;
    if (r == 0) { on[0] = (float)sn; ot[0] = st; }

    const float rb = restart_b[0];

    // loop-invariant weight chunk for the mem dot (lane r owns elems r*16..r*16+15)
    float wv[16];
    {
        const float4* p = reinterpret_cast<const float4*>(restart_w) + r * 4;
        float4 v0 = p[0], v1 = p[1], v2 = p[2], v3 = p[3];
        *(float4*)&wv[0] = v0; *(float4*)&wv[4] = v1;
        *(float4*)&wv[8] = v2; *(float4*)&wv[12] = v3;
    }
    // loop-invariant time-encoder chunks (lane r owns t = r*8..r*8+7)
    float tw[8], tb[8], rw2[8];
    {
        const float4* ptw = reinterpret_cast<const float4*>(time_w + 8 * r);
        const float4* ptb = reinterpret_cast<const float4*>(time_b + 8 * r);
        const float4* prw = reinterpret_cast<const float4*>(restart_w + M_ + 8 * r);
        *(float4*)&tw[0] = ptw[0]; *(float4*)&tw[4] = ptw[1];
        *(float4*)&tb[0] = ptb[0]; *(float4*)&tb[4] = ptb[1];
        *(float4*)&rw2[0] = prw[0]; *(float4*)&rw2[4] = prw[1];
    }

    for (int l = 0; l < L_; ++l) {
        // ---------- parallel loads ----------
        const float* __restrict__ mrow = mem + (size_t)cur_n * M_;
        float mv[16];
        {
            const float4* p = reinterpret_cast<const float4*>(mrow) + r * 4;
            float4 v0 = p[0], v1 = p[1], v2 = p[2], v3 = p[3];
            *(float4*)&mv[0] = v0; *(float4*)&mv[4] = v1;
            *(float4*)&mv[8] = v2; *(float4*)&mv[12] = v3;
        }
        const float* __restrict__ nts_row = nbr_time + (size_t)cur_n * D_;
        float tv[8];
        {
            const float4* p = reinterpret_cast<const float4*>(nts_row) + r * 2;
            float4 v0 = p[0], v1 = p[1];
            *(float4*)&tv[0] = v0; *(float4*)&tv[4] = v1;
        }
        const int cnt = nbr_cnt[cur_n];

        // elementwise time-encoder terms (identical expression to baseline)
        float cosv[8];
        #pragma unroll
        for (int i = 0; i < 8; ++i) cosv[i] = cosf(cur_t * tw[i] + tb[i]);

        // ---------- restart logit: two exact sequential relays (fused) ----------
        float runA = 0.f, runB = 0.f;
        #pragma unroll
        for (int rr = 0; rr < 8; ++rr) {
            float pA = __shfl_up(runA, 1, 8);
            float pB = __shfl_up(runB, 1, 8);
            if (r == rr) {
                if (rr > 0) { runA = pA; runB = pB; }
                #pragma unroll
                for (int i = 0; i < 16; ++i) runA += mv[i] * wv[i];   // fmac chain, exact order
                #pragma unroll
                for (int i = 0; i < 8; ++i)  runB += cosv[i] * rw2[i];
            }
        }
        const float accm = __shfl(runA, 7, 8);
        const float acct = __shfl(runB, 7, 8);
        const float logits = accm + acct + rb;
        const float p = 1.f / (1.f + expf(-logits));
        const float r_re = rand_restart[(size_t)l * NWALK + gid];
        const bool restart = r_re < p;

        // ---------- neighbor scores ----------
        float e[8];
        float lmx = -1e9f;
        #pragma unroll
        for (int i = 0; i < 8; ++i) {
            const float tj = tv[i];
            const bool  v  = (tj < cur_t) && ((8 * r + i) < cnt);
            const float s  = v ? (tj - cur_t) / 0.1f : -1e9f;   // true division
            e[i] = s;
            lmx = fmaxf(lmx, s);
        }
        // max is associative: shuffle tree is exact
        lmx = fmaxf(lmx, __shfl_xor(lmx, 1, 8));
        lmx = fmaxf(lmx, __shfl_xor(lmx, 2, 8));
        lmx = fmaxf(lmx, __shfl_xor(lmx, 4, 8));
        const bool hv = (lmx != -1e9f);   // any valid neighbor (valid scores are in [-10,0))

        #pragma unroll
        for (int i = 0; i < 8; ++i) e[i] = expf(e[i] - lmx);

        // ---------- softmax sum: exact sequential relay ----------
        float runS = 0.f;
        #pragma unroll
        for (int rr = 0; rr < 8; ++rr) {
            float pS = __shfl_up(runS, 1, 8);
            if (r == rr) {
                if (rr > 0) runS = pS;
                #pragma unroll
                for (int i = 0; i < 8; ++i) runS += e[i];   // plain adds, exact order
            }
        }
        const float ssum = __shfl(runS, 7, 8);

        // elementwise correctly-rounded divisions (identical to baseline's in-loop div)
        float q[8];
        #pragma unroll
        for (int i = 0; i < 8; ++i) q[i] = e[i] / ssum;

        const float r_nb = rand_neighbor[(size_t)l * NWALK + gid];

        // ---------- CDF relay + indicator count ----------
        float runC = 0.f;
        int   cloc = 0;
        #pragma unroll
        for (int rr = 0; rr < 8; ++rr) {
            float pC = __shfl_up(runC, 1, 8);
            if (r == rr) {
                if (rr > 0) runC = pC;
                #pragma unroll
                for (int i = 0; i < 8; ++i) {
                    runC += q[i];
                    cloc += (runC < r_nb) ? 1 : 0;
                }
            }
        }
        int idx = cloc;   // integer add is associative: tree is exact
        idx += __shfl_xor(idx, 1, 8);
        idx += __shfl_xor(idx, 2, 8);
        idx += __shfl_xor(idx, 4, 8);
        if (idx > D_ - 1) idx = D_ - 1;

        // broadcast-address loads (one request per group)
        const int   sel_id = nbr_ids[(size_t)cur_n * D_ + idx];
        const float sel_t  = nts_row[idx];
        const int   step_n = hv ? sel_id : cur_n;
        const float step_t = hv ? sel_t  : cur_t;
        cur_n = restart ? sn : step_n;
        cur_t = restart ? st : step_t;

        if (r == 0) {
            on[l + 1] = (float)cur_n;
            ot[l + 1] = cur_t;
            op[l]     = p;
        }
    }
}

extern "C" void kernel_launch(void* const* d_in, const int* in_sizes, int n_in,
                              void* d_out, int out_size, void* d_ws, size_t ws_size,
                              hipStream_t stream) {
    const int*   nbr_ids       = (const int*)  d_in[0];
    const float* nbr_time      = (const float*)d_in[1];
    const int*   nbr_cnt       = (const int*)  d_in[2];
    const int*   start_nodes   = (const int*)  d_in[3];
    const float* start_times   = (const float*)d_in[4];
    const float* memst         = (const float*)d_in[5];
    const float* time_w        = (const float*)d_in[6];
    const float* time_b        = (const float*)d_in[7];
    const float* restart_w     = (const float*)d_in[8];
    const float* restart_b     = (const float*)d_in[9];
    const float* rand_restart  = (const float*)d_in[10];
    const float* rand_neighbor = (const float*)d_in[11];

    float* out_nodes = (float*)d_out;
    float* out_times = out_nodes + (size_t)B_ * W_ * (L_ + 1);
    float* out_probs = out_times + (size_t)B_ * W_ * (L_ + 1);

    const int threads = 256;
    const int blocks  = (NWALK * K_ + threads - 1) / threads;   // 1280
    hipLaunchKernelGGL(walk_kernel, dim3(blocks), dim3(threads), 0, stream,
                       nbr_ids, nbr_time, nbr_cnt, start_nodes, start_times,
                       memst, time_w, time_b, restart_w, restart_b,
                       rand_restart, rand_neighbor,
                       out_nodes, out_times, out_probs);
}